// Round 7
// baseline (392.594 us; speedup 1.0000x reference)
//
#include <hip/hip_runtime.h>
#include <cstddef>
#include <cstdint>

constexpr int Bn    = 8;
constexpr int Hn    = 96;
constexpr int Wn    = 96;
constexpr int HWn   = Hn * Wn;       // 9216
constexpr int BHWn  = Bn * HWn;      // 73728
constexpr int B10HW = Bn * 10 * HWn; // 737280

using short8  = __attribute__((ext_vector_type(8))) short;
using ushort8 = __attribute__((ext_vector_type(8))) unsigned short;
using float4v = __attribute__((ext_vector_type(4))) float;

__device__ __forceinline__ unsigned short f2bf(float f) {
    unsigned u = __builtin_bit_cast(unsigned, f);
    u += 0x7FFFu + ((u >> 16) & 1u);   // RNE; inputs are finite
    return (unsigned short)(u >> 16);
}

// ---------------------------------------------------------------------------
// K0: pack da_w1 (OIHW fp32 [256][257][9]) into B-fragment order, bf16.
// Coalesced linear reads; scattered 2B NONTEMPORAL writes (keep packed
// weights out of the producing XCD's L2 so all 8 XCDs fetch clean lines).
// Layout: o = ((t*16+q)*64+lane)*8+j, t = (ci/32)*9+tap, q = co/16,
// lane = (co&15) + ((ci>>3)&3)*16, j = ci&7. Pad ci in [257,288) zeroed.
// ---------------------------------------------------------------------------
__global__ void k_packw(const float* __restrict__ w1, short* __restrict__ wpk)
{
    const int idx = blockIdx.x * 256 + threadIdx.x;   // 592128 real + 71424 pad
    if (idx < 592128) {
        const int co  = idx / 2313;
        const int rem = idx % 2313;
        const int ci  = rem / 9;
        const int tap = rem % 9;
        const int g   = (ci >> 3) & 3, j = ci & 7;
        const int t   = (ci >> 5) * 9 + tap;
        const int q   = co >> 4;
        const int lane = (co & 15) + (g << 4);
        __builtin_nontemporal_store((short)f2bf(w1[idx]),
                                    &wpk[(((size_t)t * 16 + q) * 64 + lane) * 8 + j]);
    } else if (idx < 663552) {
        int p = idx - 592128;              // 256 co x 9 tap x 31 pad-ci
        const int ci  = 257 + (p % 31);
        p /= 31;
        const int tap = p % 9;
        const int co  = p / 9;
        const int g   = (ci >> 3) & 3, j = ci & 7;
        const int t   = (ci >> 5) * 9 + tap;
        const int q   = co >> 4;
        const int lane = (co & 15) + (g << 4);
        __builtin_nontemporal_store((short)0,
                                    &wpk[(((size_t)t * 16 + q) * 64 + lane) * 8 + j]);
    }
}

// ---------------------------------------------------------------------------
// K1: conv3x3 257->256 +BN+ReLU + conv1x1 256->2 + softmax + *patt.
// Block: M=64 pos (2r x 32c) x N=256 co, 4 waves (wave = 64m x 64n).
// BARRIER-FREE K-loop: X staged in two phases (ci 0..127, ci 128..287) into
// a 43.8 KB LDS tile; 81 tap-iterations fully unrolled with register B
// prefetch and NO intervening barriers (3 barriers total + epilogue).
// XCD swizzle b = bx&7 keeps xh slice + wpk L2-resident per XCD.
// ---------------------------------------------------------------------------
__global__ __launch_bounds__(256, 3)
void k_bigconv5(const float* __restrict__ xh, const float* __restrict__ patt,
                const short* __restrict__ wpk, const float* __restrict__ g1,
                const float* __restrict__ b1, const float* __restrict__ w2,
                const float* __restrict__ db2,
                float* __restrict__ dm_out, float* __restrict__ s01)
{
    __shared__ __align__(16) short xs[20 * 137 * 8];  // [oct<=20][pos 4x34 pad137][8ci]

    const int tid  = threadIdx.x;
    const int lane = tid & 63;
    const int wid  = tid >> 6;          // wave id = n-quarter
    const int bx   = blockIdx.x;
    const int b    = bx & 7;            // XCD-locality swizzle
    const int r2   = bx >> 3;           // 0..143
    const int wseg = r2 % 3;
    const int hb   = r2 / 3;            // 0..47
    const int h0   = hb * 2, w0 = wseg * 32;
    const int am   = lane & 15;
    const int aq   = lane >> 4;

    float4v acc[4][4];
    #pragma unroll
    for (int i = 0; i < 4; ++i)
        #pragma unroll
        for (int j = 0; j < 4; ++j)
            acc[i][j] = float4v{0.f, 0.f, 0.f, 0.f};

    int arow[4], acol[4];
    #pragma unroll
    for (int mt = 0; mt < 4; ++mt) {
        const int m = mt * 16 + am;
        arow[mt] = m >> 5;
        acol[mt] = m & 31;
    }

    // stage nOct k-octets starting at global octet og0 (ci = og*8 + j)
    auto stage = [&](int og0, int nOct) {
        const int n = nOct * 136;
        for (int idx = tid; idx < n; idx += 256) {
            const int oct = idx / 136, pos = idx % 136;
            const int og  = og0 + oct;
            const int row = pos / 34, col = pos % 34;
            const int hh = h0 - 1 + row, ww = w0 - 1 + col;
            const bool inb = ((unsigned)hh < (unsigned)Hn) & ((unsigned)ww < (unsigned)Wn);
            const int off = hh * Wn + ww;
            ushort8 v;
            #pragma unroll
            for (int j = 0; j < 8; ++j) {
                const int ci = og * 8 + j;
                float f = 0.f;
                if (inb && ci < 257)
                    f = (ci == 0) ? patt[b * HWn + off]
                                  : xh[((size_t)b * 256 + (ci - 1)) * HWn + off];
                v[j] = f2bf(f);
            }
            *(ushort8*)&xs[(oct * 137 + pos) * 8] = v;
        }
    };

    const short8* wp = (const short8*)wpk;
    const int qb = wid * 4;             // this wave's co-16-tile base

    short8 bfr[2][4];
    #pragma unroll
    for (int nt = 0; nt < 4; ++nt)      // B for t=0
        bfr[0][nt] = wp[(size_t)(qb + nt) * 64 + lane];

    stage(0, 16);                       // phase A: ci 0..127 (cb 0..3)
    __syncthreads();

    #pragma unroll
    for (int t = 0; t < 36; ++t) {
        #pragma unroll
        for (int nt = 0; nt < 4; ++nt)
            bfr[(t + 1) & 1][nt] = wp[((size_t)(t + 1) * 16 + qb + nt) * 64 + lane];
        const int cbl = t / 9, tap = t % 9, kh = tap / 3, kw = tap % 3;
        short8 afr[4];
        #pragma unroll
        for (int mt = 0; mt < 4; ++mt)
            afr[mt] = *(const short8*)
                &xs[((cbl * 4 + aq) * 137 + (arow[mt] + kh) * 34 + acol[mt] + kw) * 8];
        #pragma unroll
        for (int mt = 0; mt < 4; ++mt)
            #pragma unroll
            for (int nt = 0; nt < 4; ++nt)
                acc[mt][nt] = __builtin_amdgcn_mfma_f32_16x16x32_bf16(
                    afr[mt], bfr[t & 1][nt], acc[mt][nt], 0, 0, 0);
    }
    __syncthreads();
    stage(16, 20);                      // phase B: ci 128..287 (cb 4..8)
    __syncthreads();

    #pragma unroll
    for (int t = 36; t < 81; ++t) {
        if (t < 80) {
            #pragma unroll
            for (int nt = 0; nt < 4; ++nt)
                bfr[(t + 1) & 1][nt] = wp[((size_t)(t + 1) * 16 + qb + nt) * 64 + lane];
        }
        const int cbl = t / 9 - 4, tap = t % 9, kh = tap / 3, kw = tap % 3;
        short8 afr[4];
        #pragma unroll
        for (int mt = 0; mt < 4; ++mt)
            afr[mt] = *(const short8*)
                &xs[((cbl * 4 + aq) * 137 + (arow[mt] + kh) * 34 + acol[mt] + kw) * 8];
        #pragma unroll
        for (int mt = 0; mt < 4; ++mt)
            #pragma unroll
            for (int nt = 0; nt < 4; ++nt)
                acc[mt][nt] = __builtin_amdgcn_mfma_f32_16x16x32_bf16(
                    afr[mt], bfr[t & 1][nt], acc[mt][nt], 0, 0, 0);
    }

    // epilogue: BN+ReLU, 1x1 (256->2), in-block reduce, softmax, s01.
    // `part` aliases xs (all LDS reads are done; barrier protects reuse).
    __syncthreads();
    float* part = (float*)xs;           // [wid(4)][m(64)][ch(2)]
    float gv[4], bv[4], wa[4], wbv[4];
    #pragma unroll
    for (int nt = 0; nt < 4; ++nt) {
        const int co = wid * 64 + nt * 16 + am;
        gv[nt]  = g1[co];
        bv[nt]  = b1[co];
        wa[nt]  = w2[co];
        wbv[nt] = w2[256 + co];
    }
    #pragma unroll
    for (int mt = 0; mt < 4; ++mt) {
        #pragma unroll
        for (int reg = 0; reg < 4; ++reg) {
            float s0 = 0.f, s1 = 0.f;
            #pragma unroll
            for (int nt = 0; nt < 4; ++nt) {
                const float y = fmaxf(fmaf(acc[mt][nt][reg], gv[nt], bv[nt]), 0.f);
                s0 = fmaf(wa[nt], y, s0);
                s1 = fmaf(wbv[nt], y, s1);
            }
            #pragma unroll
            for (int off = 1; off < 16; off <<= 1) {
                s0 += __shfl_xor(s0, off, 64);
                s1 += __shfl_xor(s1, off, 64);
            }
            if (am == 0) {
                const int m = mt * 16 + aq * 4 + reg;
                part[(wid * 64 + m) * 2 + 0] = s0;
                part[(wid * 64 + m) * 2 + 1] = s1;
            }
        }
    }
    __syncthreads();
    if (tid < 64) {
        const int m = tid, r = m >> 5, c = m & 31;
        const int off = (h0 + r) * Wn + (w0 + c);
        float d0 = db2[0], d1 = db2[1];
        #pragma unroll
        for (int w = 0; w < 4; ++w) {
            d0 += part[(w * 64 + m) * 2 + 0];
            d1 += part[(w * 64 + m) * 2 + 1];
        }
        dm_out[(size_t)(b * 2) * HWn + off]     = d0;
        dm_out[(size_t)(b * 2 + 1) * HWn + off] = d1;
        const float mx = fmaxf(d0, d1);
        const float e0 = expf(d0 - mx), e1 = expf(d1 - mx);
        const float pa = patt[b * HWn + off];
        const float inv = pa / (e0 + e1);
        s01[b * HWn + off]        = e0 * inv;
        s01[BHWn + b * HWn + off] = e1 * inv;
    }
}

// ---------------------------------------------------------------------------
// K4: branch = ReLU(BN(conv3x3 20->10)) -> ReLU(BN(conv1x1 10->10)), tiled,
// with up/lo composition fused into staging.
// z=0: [parent*s0, h1](rel)  z=1: [parent*s1, h2](rel)
// z=2: [h1, (sum pn 1..4)*(sum pa 1..4)](cu)
// z=3: [h2, (sum pn 5..6)*(sum pa 5..6)](cl)
// ---------------------------------------------------------------------------
struct BranchW  { const float *w1, *g1, *b1, *w2, *g2, *b2; };
struct BranchW3 { BranchW p[3]; };

__global__ __launch_bounds__(256)
void k_branch(BranchW3 P, const float* __restrict__ parent, const float* __restrict__ h_nodes,
              const float* __restrict__ s01, const float* __restrict__ pn,
              const float* __restrict__ pa, float* __restrict__ bout)
{
    const int z  = blockIdx.y;
    const int pi = (z < 2) ? 0 : (z - 1);
    __shared__ float xt[20][10][34];
    __shared__ float paSum[340];
    __shared__ __align__(16) float wlt[9 * 20 * 12];
    __shared__ float w2l[100], g1l[10], b1l[10], g2l[10], b2l[10];

    const BranchW& Pw = P.p[pi];
    const int tid = threadIdx.x;
    for (int idx = tid; idx < 2160; idx += 256) {
        const int co = idx % 12, rem = idx / 12, ci = rem % 20, tap = rem / 20;
        wlt[idx] = (co < 10) ? Pw.w1[(co * 20 + ci) * 9 + tap] : 0.f;
    }
    if (tid < 100) w2l[tid] = Pw.w2[tid];
    if (tid < 10) {
        g1l[tid] = Pw.g1[tid]; b1l[tid] = Pw.b1[tid];
        g2l[tid] = Pw.g2[tid]; b2l[tid] = Pw.b2[tid];
    }

    const int bx = blockIdx.x;
    const int tw = bx % 3, th = (bx / 3) % 12, b = bx / 36;
    const int h0 = th * 8, w0 = tw * 32;

    const float* Ab;
    const float* sc = nullptr;
    const float* Bb = nullptr;
    int k0 = 0, k1 = -1;
    if (z == 0)      { Ab = parent; sc = s01;        Bb = h_nodes + (size_t)1 * B10HW; }
    else if (z == 1) { Ab = parent; sc = s01 + BHWn; Bb = h_nodes + (size_t)2 * B10HW; }
    else if (z == 2) { Ab = h_nodes + (size_t)1 * B10HW; k0 = 1; k1 = 4; }
    else             { Ab = h_nodes + (size_t)2 * B10HW; k0 = 5; k1 = 6; }

    if (z >= 2) {
        for (int idx = tid; idx < 340; idx += 256) {
            const int col = idx % 34, row = idx / 34;
            const int hh = h0 - 1 + row, ww = w0 - 1 + col;
            float s = 0.f;
            if (((unsigned)hh < (unsigned)Hn) & ((unsigned)ww < (unsigned)Wn)) {
                const int off = hh * Wn + ww;
                for (int k = k0; k <= k1; ++k)
                    s += pa[(size_t)(k * Bn + b) * HWn + off];
            }
            paSum[idx] = s;
        }
    }
    __syncthreads();

    for (int idx = tid; idx < 6800; idx += 256) {
        const int col = idx % 34, rem = idx / 34, row = rem % 10, ch = rem / 10;
        const int hh = h0 - 1 + row, ww = w0 - 1 + col;
        float v = 0.f;
        if (((unsigned)hh < (unsigned)Hn) & ((unsigned)ww < (unsigned)Wn)) {
            const int off = hh * Wn + ww;
            if (ch < 10) {
                v = Ab[((size_t)b * 10 + ch) * HWn + off];
                if (sc) v *= sc[b * HWn + off];
            } else if (z < 2) {
                v = Bb[((size_t)b * 10 + (ch - 10)) * HWn + off];
            } else {
                float s = 0.f;
                for (int k = k0; k <= k1; ++k)
                    s += pn[((size_t)(k * Bn + b) * 10 + (ch - 10)) * HWn + off];
                v = s * paSum[row * 34 + col];
            }
        }
        ((float*)xt)[idx] = v;
    }
    __syncthreads();

    const int r = tid >> 5, c = tid & 31;
    float a0 = 0, a1 = 0, a2 = 0, a3 = 0, a4 = 0, a5 = 0, a6 = 0, a7 = 0, a8 = 0, a9 = 0;
    #pragma unroll
    for (int tap = 0; tap < 9; ++tap) {
        const int kh = tap / 3, kw = tap % 3;
        #pragma unroll
        for (int ci = 0; ci < 20; ++ci) {
            const float xv = xt[ci][r + kh][c + kw];
            const float4 wA = *(const float4*)&wlt[(tap * 20 + ci) * 12];
            const float4 wB = *(const float4*)&wlt[(tap * 20 + ci) * 12 + 4];
            const float2 wC = *(const float2*)&wlt[(tap * 20 + ci) * 12 + 8];
            a0 = fmaf(wA.x, xv, a0); a1 = fmaf(wA.y, xv, a1);
            a2 = fmaf(wA.z, xv, a2); a3 = fmaf(wA.w, xv, a3);
            a4 = fmaf(wB.x, xv, a4); a5 = fmaf(wB.y, xv, a5);
            a6 = fmaf(wB.z, xv, a6); a7 = fmaf(wB.w, xv, a7);
            a8 = fmaf(wC.x, xv, a8); a9 = fmaf(wC.y, xv, a9);
        }
    }
    float acc[10] = {a0, a1, a2, a3, a4, a5, a6, a7, a8, a9};
    float y[10];
    #pragma unroll
    for (int co = 0; co < 10; ++co)
        y[co] = fmaxf(fmaf(acc[co], g1l[co], b1l[co]), 0.f);
    const int hw = (h0 + r) * Wn + (w0 + c);
    #pragma unroll
    for (int co = 0; co < 10; ++co) {
        float s = 0.f;
        #pragma unroll
        for (int i = 0; i < 10; ++i) s = fmaf(w2l[co * 10 + i], y[i], s);
        s = fmaxf(fmaf(s, g2l[co], b2l[co]), 0.f);
        bout[(size_t)z * B10HW + ((size_t)b * 10 + co) * HWn + hw] = s;
    }
}

// ---------------------------------------------------------------------------
// K5: ConvGRU (1x1 kernels). z = node 0/1/2.
// ---------------------------------------------------------------------------
__global__ void k_gru(const float* __restrict__ f_nodes, const float* __restrict__ h_nodes,
                      const float* __restrict__ p_nodes, const float* __restrict__ bout,
                      const float* __restrict__ gw, const float* __restrict__ gb,
                      const float* __restrict__ cw, const float* __restrict__ cg,
                      const float* __restrict__ cb, float* __restrict__ out)
{
    const int z = blockIdx.y;
    __shared__ float gwl[40], cwl[200], gbl[2], cgl[10], cbl[10];
    if (threadIdx.x < 40)  gwl[threadIdx.x] = gw[z * 40 + threadIdx.x];
    if (threadIdx.x < 200) cwl[threadIdx.x] = cw[z * 200 + threadIdx.x];
    if (threadIdx.x < 2)   gbl[threadIdx.x] = gb[z * 2 + threadIdx.x];
    if (threadIdx.x < 10) {
        cgl[threadIdx.x] = cg[z * 10 + threadIdx.x];
        cbl[threadIdx.x] = cb[z * 10 + threadIdx.x];
    }
    __syncthreads();

    const int p = blockIdx.x * 256 + threadIdx.x;
    const int b = p / HWn, hw = p % HWn;
    float x[10], h[10];
    #pragma unroll
    for (int c = 0; c < 10; ++c) {
        const size_t idx = ((size_t)b * 10 + c) * HWn + hw;
        if (z == 0)      x[c] = f_nodes[idx] + p_nodes[idx];
        else if (z == 1) x[c] = bout[(size_t)2 * B10HW + idx] + bout[idx];
        else             x[c] = bout[(size_t)3 * B10HW + idx] + bout[(size_t)1 * B10HW + idx];
        h[c] = h_nodes[(size_t)z * B10HW + idx];
    }
    float g0 = gbl[0], g1 = gbl[1];
    #pragma unroll
    for (int c = 0; c < 10; ++c) {
        g0 = fmaf(gwl[c],      x[c], g0);
        g0 = fmaf(gwl[10 + c], h[c], g0);
        g1 = fmaf(gwl[20 + c], x[c], g1);
        g1 = fmaf(gwl[30 + c], h[c], g1);
    }
    const float r = 1.f / (1.f + expf(-g0));
    const float u = 1.f / (1.f + expf(-g1));
    #pragma unroll
    for (int o = 0; o < 10; ++o) {
        float s = 0.f;
        #pragma unroll
        for (int c = 0; c < 10; ++c) {
            s = fmaf(cwl[o * 20 + c],      x[c],     s);
            s = fmaf(cwl[o * 20 + 10 + c], r * h[c], s);
        }
        s = fmaxf(fmaf(s, cgl[o], cbl[o]), 0.f);
        out[(size_t)z * B10HW + ((size_t)b * 10 + o) * HWn + hw] =
            (1.f - u) * h[o] + u * s;
    }
}

// ---------------------------------------------------------------------------
extern "C" void kernel_launch(void* const* d_in, const int* in_sizes, int n_in,
                              void* d_out, int out_size, void* d_ws, size_t ws_size,
                              hipStream_t stream)
{
    (void)in_sizes; (void)n_in; (void)out_size; (void)ws_size;

    const float* f_nodes = (const float*)d_in[0];
    const float* h_nodes = (const float*)d_in[1];
    const float* p_nodes = (const float*)d_in[2];
    const float* xh      = (const float*)d_in[3];
    const float* f_atts  = (const float*)d_in[4];
    const float* p_atts  = (const float*)d_in[5];
    const float* da_w1   = (const float*)d_in[6];
    const float* da_g1   = (const float*)d_in[7];
    const float* da_b1   = (const float*)d_in[8];
    const float* da_w2   = (const float*)d_in[9];
    const float* da_b2   = (const float*)d_in[10];

    BranchW3 P;
    for (int i = 0; i < 3; ++i) {
        P.p[i].w1 = (const float*)d_in[11 + 6 * i + 0];
        P.p[i].g1 = (const float*)d_in[11 + 6 * i + 1];
        P.p[i].b1 = (const float*)d_in[11 + 6 * i + 2];
        P.p[i].w2 = (const float*)d_in[11 + 6 * i + 3];
        P.p[i].g2 = (const float*)d_in[11 + 6 * i + 4];
        P.p[i].b2 = (const float*)d_in[11 + 6 * i + 5];
    }
    const float* gru_gw = (const float*)d_in[29];
    const float* gru_gb = (const float*)d_in[30];
    const float* gru_cw = (const float*)d_in[31];
    const float* gru_cg = (const float*)d_in[32];
    const float* gru_cb = (const float*)d_in[33];

    float* out    = (float*)d_out;
    float* dm_out = out + (size_t)3 * B10HW;     // stack(n0,n1,n2) then dm

    float* ws     = (float*)d_ws;
    float* s01    = ws;                 // 2*BHWn
    float* bout   = s01 + 2 * BHWn;     // 4*B10HW  (d0, d1, cu, cl)
    // wpk (1.33 MB of bf16) aliases the bout region: written by k_packw,
    // read only by k_bigconv5; bout is written later by k_branch.
    short* wpk    = (short*)bout;

    const float* patt   = f_atts + BHWn;     // f_atts[1]
    const float* parent = f_nodes + B10HW;   // f_nodes[1]

    k_packw<<<dim3(2592), 256, 0, stream>>>(da_w1, wpk);
    k_bigconv5<<<dim3(1152), 256, 0, stream>>>(xh, patt, wpk, da_g1, da_b1,
                                               da_w2, da_b2, dm_out, s01);
    k_branch<<<dim3(288, 4), 256, 0, stream>>>(P, parent, h_nodes, s01,
                                               p_nodes, p_atts, bout);
    k_gru<<<dim3(288, 3), 256, 0, stream>>>(f_nodes, h_nodes, p_nodes, bout,
                                            gru_gw, gru_gb, gru_cw, gru_cg, gru_cb, out);
}